// Round 1
// 699.110 us; speedup vs baseline: 1.0326x; 1.0326x over previous
//
#include <hip/hip_runtime.h>

typedef _Float16 half8 __attribute__((ext_vector_type(8)));
typedef _Float16 half4 __attribute__((ext_vector_type(4)));
typedef float f32x4 __attribute__((ext_vector_type(4)));

// async global->LDS 16B: LDS dest must be wave-uniform base + lane*16.
__device__ __forceinline__ void gl2lds16(const _Float16* g, _Float16* l) {
  __builtin_amdgcn_global_load_lds((const __attribute__((address_space(1))) void*)g,
                                   (__attribute__((address_space(3))) void*)l, 16, 0, 0);
}

__device__ __forceinline__ void nt_store4(float* p, f32x4 v) {
  __builtin_nontemporal_store(v, (f32x4*)p);
}

// ---------------- fp32 -> fp16 convert ----------------
__global__ __launch_bounds__(256) void cvt_kernel(const float* __restrict__ in,
                                                  _Float16* __restrict__ out, int n) {
  int i = (blockIdx.x * 256 + threadIdx.x) * 8;
  if (i >= n) return;
  float4 a = *(const float4*)(in + i);
  float4 b = *(const float4*)(in + i + 4);
  half8 o;
  o[0] = (_Float16)a.x; o[1] = (_Float16)a.y; o[2] = (_Float16)a.z; o[3] = (_Float16)a.w;
  o[4] = (_Float16)b.x; o[5] = (_Float16)b.y; o[6] = (_Float16)b.z; o[7] = (_Float16)b.w;
  *(half8*)(out + i) = o;
}

// ---------- fp32 [K][N] -> fp16 [N][K] transpose+convert, 64x64 tiles ----------
__global__ __launch_bounds__(256) void cvtT_kernel(const float* __restrict__ in,
                                                   _Float16* __restrict__ out,
                                                   int K, int N) {
  __shared__ float Ts[64][65];
  const int k0 = blockIdx.y * 64, n0 = blockIdx.x * 64;
  const int t = threadIdx.x;
  const int r = t >> 4, c = (t & 15) * 4;
#pragma unroll
  for (int i = 0; i < 4; i++) {
    float4 v = *(const float4*)(in + (size_t)(k0 + r + i * 16) * N + n0 + c);
    Ts[r + i * 16][c] = v.x; Ts[r + i * 16][c + 1] = v.y;
    Ts[r + i * 16][c + 2] = v.z; Ts[r + i * 16][c + 3] = v.w;
  }
  __syncthreads();
  const int nl = t >> 2, kq = (t & 3) * 16;
  half8 o0, o1;
#pragma unroll
  for (int j = 0; j < 8; j++) {
    o0[j] = (_Float16)Ts[kq + j][nl];
    o1[j] = (_Float16)Ts[kq + 8 + j][nl];
  }
  *(half8*)(out + (size_t)(n0 + nl) * K + k0 + kq) = o0;
  *(half8*)(out + (size_t)(n0 + nl) * K + k0 + kq + 8) = o1;
}

// ---------- V [bh][s][64] -> V^T [bh][64][s] fp16 transpose, 64x64 tiles ----------
__global__ __launch_bounds__(256) void vtrans_kernel(const _Float16* __restrict__ v,
                                                     _Float16* __restrict__ vt) {
  __shared__ _Float16 Ht[64][72];
  const int s0 = blockIdx.x * 64;
  const _Float16* vb = v + (size_t)blockIdx.y * 131072;
  _Float16* vtb = vt + (size_t)blockIdx.y * 131072;
  const int t = threadIdx.x;
  const int sl = t >> 3, dq = (t & 7) * 8;
  *(half8*)&Ht[sl][dq] = *(const half8*)(vb + (s0 + sl) * 64 + dq);
  *(half8*)&Ht[sl + 32][dq] = *(const half8*)(vb + (s0 + sl + 32) * 64 + dq);
  __syncthreads();
  const int dl = t >> 2, sq = (t & 3) * 16;
  half8 o0, o1;
#pragma unroll
  for (int j = 0; j < 8; j++) {
    o0[j] = Ht[sq + j][dl];
    o1[j] = Ht[sq + 8 + j][dl];
  }
  *(half8*)(vtb + (size_t)dl * 2048 + s0 + sq) = o0;
  *(half8*)(vtb + (size_t)dl * 2048 + s0 + sq + 8) = o1;
}

// ---------------- m97-style f16 MFMA GEMM, B pre-transposed [N][K] ----------------
template <int MODE, int BN>
__global__ __launch_bounds__(256) void gemm16(const _Float16* __restrict__ A,
                                              const _Float16* __restrict__ B,
                                              float* __restrict__ Cf,
                                              _Float16* __restrict__ Ch,
                                              int M, int N, int K) {
  constexpr int MI = (BN == 128) ? 4 : 2;
  __shared__ __align__(16) _Float16 As[128 * 32];
  __shared__ __align__(16) _Float16 Bs[BN * 32];
  const int tid = threadIdx.x;
  const int lane = tid & 63;
  const int wid = tid >> 6;
  const int quad = lane >> 4;
  const int l16 = lane & 15;
  const int mbase = (BN == 128) ? (wid >> 1) * 64 : wid * 32;
  const int nbase = (BN == 128) ? (wid & 1) * 64 : 0;
  const int m0 = blockIdx.y * 128;
  const int n0 = blockIdx.x * BN;

  f32x4 acc[MI][4];
  const f32x4 fz = {0.f, 0.f, 0.f, 0.f};
#pragma unroll
  for (int i = 0; i < MI; i++)
#pragma unroll
    for (int j = 0; j < 4; j++) acc[i][j] = fz;

  const int srow = tid >> 2;
  const int kq = (tid & 3) * 8;

  for (int kt = 0; kt < K; kt += 32) {
    gl2lds16(A + (size_t)(m0 + srow) * K + kt + kq, &As[tid * 8]);
    gl2lds16(A + (size_t)(m0 + 64 + srow) * K + kt + kq, &As[2048 + tid * 8]);
    gl2lds16(B + (size_t)(n0 + srow) * K + kt + kq, &Bs[tid * 8]);
    if (BN == 128)
      gl2lds16(B + (size_t)(n0 + 64 + srow) * K + kt + kq, &Bs[2048 + tid * 8]);
    __syncthreads();
    half8 af[MI], bf[4];
#pragma unroll
    for (int mi = 0; mi < MI; mi++)
      af[mi] = *(const half8*)&As[(mbase + mi * 16 + l16) * 32 + quad * 8];
#pragma unroll
    for (int ni = 0; ni < 4; ni++)
      bf[ni] = *(const half8*)&Bs[(nbase + ni * 16 + l16) * 32 + quad * 8];
#pragma unroll
    for (int mi = 0; mi < MI; mi++)
#pragma unroll
      for (int ni = 0; ni < 4; ni++)
        acc[mi][ni] = __builtin_amdgcn_mfma_f32_16x16x32_f16(af[mi], bf[ni], acc[mi][ni], 0, 0, 0);
    __syncthreads();
  }

#pragma unroll
  for (int mi = 0; mi < MI; mi++)
#pragma unroll
    for (int ni = 0; ni < 4; ni++)
#pragma unroll
      for (int r = 0; r < 4; r++) {
        int row = m0 + mbase + mi * 16 + quad * 4 + r;
        int col = n0 + nbase + ni * 16 + l16;
        float v = acc[mi][ni][r];
        if (MODE == 0) {
          Cf[(size_t)row * N + col] = v;
        } else {
          int which = col >> 10, h = (col >> 6) & 15, d = col & 63;
          int b = row >> 11, s = row & 2047;
          Ch[((((size_t)(which * 2 + b) * 16 + h) * 2048) + s) * 64 + d] = (_Float16)v;
        }
      }
}

// ---------------- fused causal attention, no-max softmax ----------------
// 2-phase pipelined (T3-minimal): double-buffered K/V staging, ONE barrier/tile.
// Ps is wave-private (wave wid owns rows wid*16..wid*16+15) -> no mid barrier.
// w written via coalesced nontemporal f32x4 from the fp16 Ps stripe.
// qt = 31 - blockIdx.x: heavy blocks launch first (tail fix).
__global__ __launch_bounds__(256) void attn_kernel(const _Float16* __restrict__ qkv,
                                                   const _Float16* __restrict__ vt,
                                                   float* __restrict__ w_out,
                                                   _Float16* __restrict__ o_buf) {
  const int qt = 31 - blockIdx.x;
  const int bh = blockIdx.y;
  const int tid = threadIdx.x;
  const int lane = tid & 63;
  const int wid = tid >> 6;
  const int quad = lane >> 4;
  const int l16 = lane & 15;

  const _Float16* qp = qkv + (size_t)bh * 131072;
  const _Float16* kp = qp + 4194304;
  const _Float16* vtb = vt + (size_t)bh * 131072;

  __shared__ __align__(16) _Float16 Ks[2][4096];  // [buf][chunk d0/d1][s][32]
  __shared__ __align__(16) _Float16 Vs[2][4096];  // [buf][chunk s0/s1][d][32]
  __shared__ __align__(16) _Float16 Ps[64][72];

  const int qrow = qt * 64 + wid * 16 + l16;
  const half8 qa0 = *(const half8*)(qp + qrow * 64 + quad * 8);
  const half8 qa1 = *(const half8*)(qp + qrow * 64 + 32 + quad * 8);

  const int srow = tid >> 2;        // 0..63
  const int blk8 = (tid & 3) * 8;
  const float sc = 0.125f;
  const f32x4 fz = {0.f, 0.f, 0.f, 0.f};
  const int lrow0 = wid * 16 + quad * 4;

  float* wbase = w_out + (size_t)bh * 4194304 + (size_t)qt * 131072;

  // ---- zerofill above-diagonal first: independent streaming store traffic,
  // issued early so it retires under pass-1 compute. Nontemporal: don't evict K/V.
  {
    const int rr = tid >> 4, cc = (tid & 15) * 4;
    for (int kt = qt + 1; kt < 32; kt++) {
      float* wz = wbase + (size_t)kt * 64 + cc;
#pragma unroll
      for (int p = 0; p < 4; p++)
        nt_store4(wz + (size_t)(p * 16 + rr) * 2048, fz);
    }
  }

  float lsum[4] = {0.f, 0.f, 0.f, 0.f};

  // ---- pass 1: row sums of exp(s). 2-phase pipeline, 1 barrier/tile ----
  int cur = 0;
  gl2lds16(kp + (size_t)srow * 64 + blk8, &Ks[0][tid * 8]);
  gl2lds16(kp + (size_t)srow * 64 + 32 + blk8, &Ks[0][2048 + tid * 8]);
  __syncthreads();
  for (int kt = 0; kt <= qt; kt++) {
    if (kt < qt) {  // prefetch t+1 into other buffer; latency hides under compute
      gl2lds16(kp + (size_t)((kt + 1) * 64 + srow) * 64 + blk8, &Ks[cur ^ 1][tid * 8]);
      gl2lds16(kp + (size_t)((kt + 1) * 64 + srow) * 64 + 32 + blk8, &Ks[cur ^ 1][2048 + tid * 8]);
    }
    f32x4 sacc[4];
#pragma unroll
    for (int ni = 0; ni < 4; ni++) {
      half8 kb0 = *(const half8*)&Ks[cur][(ni * 16 + l16) * 32 + quad * 8];
      half8 kb1 = *(const half8*)&Ks[cur][2048 + (ni * 16 + l16) * 32 + quad * 8];
      f32x4 s = fz;
      s = __builtin_amdgcn_mfma_f32_16x16x32_f16(qa0, kb0, s, 0, 0, 0);
      s = __builtin_amdgcn_mfma_f32_16x16x32_f16(qa1, kb1, s, 0, 0, 0);
      sacc[ni] = s;
    }
    if (kt < qt) {
#pragma unroll
      for (int ni = 0; ni < 4; ni++)
#pragma unroll
        for (int r = 0; r < 4; r++) lsum[r] += __expf(sacc[ni][r] * sc);
    } else {  // diagonal tile: mask col > row
#pragma unroll
      for (int ni = 0; ni < 4; ni++)
#pragma unroll
        for (int r = 0; r < 4; r++) {
          if (ni * 16 + l16 <= lrow0 + r) lsum[r] += __expf(sacc[ni][r] * sc);
        }
    }
    __syncthreads();
    cur ^= 1;
  }
  float invl[4];
#pragma unroll
  for (int r = 0; r < 4; r++) {
    float s = lsum[r];
    s += __shfl_xor(s, 1); s += __shfl_xor(s, 2);
    s += __shfl_xor(s, 4); s += __shfl_xor(s, 8);
    invl[r] = 1.0f / s;
  }

  f32x4 oacc[4];
#pragma unroll
  for (int di = 0; di < 4; di++) oacc[di] = fz;

  // ---- pass 2: recompute S, normalized P -> Ps (fp16), PV, w export ----
  cur = 0;
  gl2lds16(kp + (size_t)srow * 64 + blk8, &Ks[0][tid * 8]);
  gl2lds16(kp + (size_t)srow * 64 + 32 + blk8, &Ks[0][2048 + tid * 8]);
  gl2lds16(vtb + (size_t)srow * 2048 + blk8, &Vs[0][tid * 8]);
  gl2lds16(vtb + (size_t)srow * 2048 + 32 + blk8, &Vs[0][2048 + tid * 8]);
  __syncthreads();
  for (int kt = 0; kt <= qt; kt++) {
    if (kt < qt) {
      const int kn = kt + 1;
      gl2lds16(kp + (size_t)(kn * 64 + srow) * 64 + blk8, &Ks[cur ^ 1][tid * 8]);
      gl2lds16(kp + (size_t)(kn * 64 + srow) * 64 + 32 + blk8, &Ks[cur ^ 1][2048 + tid * 8]);
      gl2lds16(vtb + (size_t)srow * 2048 + kn * 64 + blk8, &Vs[cur ^ 1][tid * 8]);
      gl2lds16(vtb + (size_t)srow * 2048 + kn * 64 + 32 + blk8, &Vs[cur ^ 1][2048 + tid * 8]);
    }
    f32x4 sacc[4];
#pragma unroll
    for (int ni = 0; ni < 4; ni++) {
      half8 kb0 = *(const half8*)&Ks[cur][(ni * 16 + l16) * 32 + quad * 8];
      half8 kb1 = *(const half8*)&Ks[cur][2048 + (ni * 16 + l16) * 32 + quad * 8];
      f32x4 s = fz;
      s = __builtin_amdgcn_mfma_f32_16x16x32_f16(qa0, kb0, s, 0, 0, 0);
      s = __builtin_amdgcn_mfma_f32_16x16x32_f16(qa1, kb1, s, 0, 0, 0);
      sacc[ni] = s;
    }
#pragma unroll
    for (int ni = 0; ni < 4; ni++)
#pragma unroll
      for (int r = 0; r < 4; r++) {
        int lrw = lrow0 + r;
        int col = ni * 16 + l16;
        float p = __expf(sacc[ni][r] * sc) * invl[r];
        if (kt == qt && col > lrw) p = 0.0f;
        Ps[lrw][col] = (_Float16)p;  // wave-private stripe; no barrier needed
      }
    // PV first (critical path for oacc)
#pragma unroll
    for (int kk = 0; kk < 2; kk++) {
      half8 pa = *(const half8*)&Ps[wid * 16 + l16][kk * 32 + quad * 8];
#pragma unroll
      for (int di = 0; di < 4; di++) {
        half8 vb = *(const half8*)&Vs[cur][kk * 2048 + (di * 16 + l16) * 32 + quad * 8];
        oacc[di] = __builtin_amdgcn_mfma_f32_16x16x32_f16(pa, vb, oacc[di], 0, 0, 0);
      }
    }
    // w export: wave re-reads its own Ps stripe, 4x f32x4 nt stores (64B/4-lane runs)
    {
      const int erow = lane >> 2;
      const int ec = (lane & 3) * 4;
      const _Float16* prow = &Ps[wid * 16 + erow][0];
      float* wrow = wbase + (size_t)(wid * 16 + erow) * 2048 + kt * 64;
#pragma unroll
      for (int j = 0; j < 4; j++) {
        half4 h = *(const half4*)(prow + j * 16 + ec);
        f32x4 o;
        o[0] = (float)h[0]; o[1] = (float)h[1]; o[2] = (float)h[2]; o[3] = (float)h[3];
        nt_store4(wrow + j * 16 + ec, o);
      }
    }
    __syncthreads();
    cur ^= 1;
  }

  const int b = bh >> 4, h = bh & 15;
#pragma unroll
  for (int di = 0; di < 4; di++)
#pragma unroll
    for (int r = 0; r < 4; r++) {
      int s = qt * 64 + lrow0 + r;
      int d = di * 16 + l16;
      o_buf[((size_t)(b * 2048 + s) * 16 + h) * 64 + d] = (_Float16)oacc[di][r];
    }
}

extern "C" void kernel_launch(void* const* d_in, const int* in_sizes, int n_in,
                              void* d_out, int out_size, void* d_ws, size_t ws_size,
                              hipStream_t stream) {
  const float* x = (const float*)d_in[0];
  const float* w_qkv = (const float*)d_in[1];
  const float* w_proj = (const float*)d_in[2];
  float* out = (float*)d_out;
  float* w_attn = out + (size_t)4194304;

  // ws (bytes): x16 0..8M | wqkvT 8..14M | wprojT 14..16M | qkv 16..40M |
  //             vT 40..48M | o 48..56M
  char* ws = (char*)d_ws;
  _Float16* x16 = (_Float16*)ws;
  _Float16* wqkvT = (_Float16*)(ws + (size_t)(8 << 20));
  _Float16* wprojT = (_Float16*)(ws + (size_t)(14 << 20));
  _Float16* qkvb = (_Float16*)(ws + (size_t)(16 << 20));
  _Float16* vT = (_Float16*)(ws + (size_t)(40 << 20));
  _Float16* ob = (_Float16*)(ws + (size_t)(48 << 20));

  cvt_kernel<<<2048, 256, 0, stream>>>(x, x16, 4194304);
  cvtT_kernel<<<dim3(48, 16), 256, 0, stream>>>(w_qkv, wqkvT, 1024, 3072);
  cvtT_kernel<<<dim3(16, 16), 256, 0, stream>>>(w_proj, wprojT, 1024, 1024);

  gemm16<1, 128><<<dim3(24, 32), 256, 0, stream>>>(x16, wqkvT, nullptr, qkvb, 4096, 3072, 1024);
  vtrans_kernel<<<dim3(32, 32), 256, 0, stream>>>(qkvb + (size_t)2 * 4194304, vT);
  attn_kernel<<<dim3(32, 32), 256, 0, stream>>>(qkvb, vT, w_attn, ob);
  gemm16<0, 64><<<dim3(16, 32), 256, 0, stream>>>(ob, wprojT, out, nullptr, 4096, 1024, 1024);
}